// Round 11
// baseline (394.675 us; speedup 1.0000x reference)
//
#include <hip/hip_runtime.h>

#define NODE_DIM 128
#define NUM_IRREPS 224
#define SPH_DIM 480
#define HIDDEN 576   // NODE_DIM + 2*NUM_IRREPS
#define NUM_BASIS 20
#define N_NODES 10000
#define N_EDGES 160000
#define NPB 4        // nodes per block in node MLP
#define EB 16        // edges per window (block)
#define NT 36        // N-tiles (576/16)
#define IRP 233      // pair row stride in words (odd -> bank-conflict-free rows)
#define SCP 138      // scal row stride in shorts (69 words, odd)

typedef __attribute__((ext_vector_type(8))) short short8v;   // 8 bf16
typedef __attribute__((ext_vector_type(4))) float f32x4;

__device__ __forceinline__ unsigned short f2bf(float f) {
    unsigned int u = __builtin_bit_cast(unsigned int, f);
    u = (u + 0x7fff + ((u >> 16) & 1)) >> 16;   // RNE
    return (unsigned short)u;
}
__device__ __forceinline__ float bf2f(unsigned short h) {
    unsigned int u = ((unsigned int)h) << 16;
    return __builtin_bit_cast(float, u);
}

// ---------------- fused prep: copy x->out, histogram, bfrag ----------------
// counts must be zeroed beforehand (hipMemsetAsync).
__global__ __launch_bounds__(256) void prep_kernel(
    const float* __restrict__ xs, const float* __restrict__ xsp,
    float* __restrict__ out,
    const int* __restrict__ eidx, int* __restrict__ counts,
    const float* __restrict__ Wr, unsigned short* __restrict__ bfrag) {
    const int stride = gridDim.x * blockDim.x;
    const int gt = blockIdx.x * blockDim.x + threadIdx.x;
    // copy outputs' base
    for (int i = gt; i < N_NODES * NODE_DIM; i += stride) out[i] = xs[i];
    float* o2 = out + (size_t)N_NODES * NODE_DIM;
    for (int i = gt; i < N_NODES * SPH_DIM; i += stride) o2[i] = xsp[i];
    // histogram by src
    if (gt < N_EDGES) atomicAdd(&counts[eidx[gt]], 1);
    // B-frag prep (last block): lane l holds col (l&15), k=(l>>4)*8+j
    if (blockIdx.x == gridDim.x - 1) {
        for (int idx = threadIdx.x; idx < NT * 64; idx += 256) {
            const int nt = idx >> 6, l = idx & 63;
            const int col = nt * 16 + (l & 15);
            const int kb = (l >> 4) * 8;
            #pragma unroll
            for (int j = 0; j < 8; ++j) {
                const int k = kb + j;
                bfrag[(size_t)idx * 8 + j] = (k < NUM_BASIS) ? f2bf(Wr[k * HIDDEN + col]) : (unsigned short)0;
            }
        }
    }
}

// ---------------- node MLP: scalar_out = silu(x@W1+b1)@W2+b2 ----------------
__global__ __launch_bounds__(128) void node_mlp(
    const float* __restrict__ x,
    const float* __restrict__ W1, const float* __restrict__ b1,
    const float* __restrict__ W2, const float* __restrict__ b2,
    float* __restrict__ so) {
    __shared__ float xs[NPB][NODE_DIM];
    __shared__ float hs[NPB][NODE_DIM];
    const int tid = threadIdx.x;
    const int n0 = blockIdx.x * NPB;

    #pragma unroll
    for (int n = 0; n < NPB; ++n) {
        int node = n0 + n;
        xs[n][tid] = (node < N_NODES) ? x[(size_t)node * NODE_DIM + tid] : 0.f;
    }
    __syncthreads();

    float acc[NPB];
    #pragma unroll
    for (int n = 0; n < NPB; ++n) acc[n] = b1[tid];
    for (int k = 0; k < NODE_DIM; ++k) {
        float w = W1[k * NODE_DIM + tid];
        #pragma unroll
        for (int n = 0; n < NPB; ++n) acc[n] = fmaf(xs[n][k], w, acc[n]);
    }
    #pragma unroll
    for (int n = 0; n < NPB; ++n) {
        float v = acc[n];
        hs[n][tid] = v / (1.f + __expf(-v));
    }
    __syncthreads();

    for (int j = tid; j < HIDDEN; j += 128) {
        float a2[NPB];
        #pragma unroll
        for (int n = 0; n < NPB; ++n) a2[n] = b2[j];
        for (int k = 0; k < NODE_DIM; ++k) {
            float w = W2[k * HIDDEN + j];
            #pragma unroll
            for (int n = 0; n < NPB; ++n) a2[n] = fmaf(hs[n][k], w, a2[n]);
        }
        #pragma unroll
        for (int n = 0; n < NPB; ++n) {
            int node = n0 + n;
            if (node < N_NODES) so[(size_t)node * HIDDEN + j] = a2[n];
        }
    }
}

// ---------------- CSR scan / scatter ----------------
__global__ __launch_bounds__(1024) void scan_kernel(const int* __restrict__ counts,
                                                    int* __restrict__ offsets,
                                                    int* __restrict__ cursor) {
    __shared__ int wsum[16];
    const int tid = threadIdx.x;
    int vals[10];
    int run = 0;
    #pragma unroll
    for (int i = 0; i < 10; ++i) {
        int idx = tid * 10 + i;
        int c = (idx < N_NODES) ? counts[idx] : 0;
        vals[i] = run;
        run += c;
    }
    const int lane = tid & 63, w = tid >> 6;
    int inc = run;
    #pragma unroll
    for (int off = 1; off < 64; off <<= 1) {
        int v = __shfl_up(inc, off);
        if (lane >= off) inc += v;
    }
    if (lane == 63) wsum[w] = inc;
    __syncthreads();
    if (w == 0) {
        int v = (lane < 16) ? wsum[lane] : 0;
        #pragma unroll
        for (int off = 1; off < 16; off <<= 1) {
            int u = __shfl_up(v, off);
            if (lane >= off) v += u;
        }
        if (lane < 16) wsum[lane] = v;
    }
    __syncthreads();
    const int wbase = (w > 0) ? wsum[w - 1] : 0;
    const int base = wbase + inc - run;   // exclusive prefix
    #pragma unroll
    for (int i = 0; i < 10; ++i) {
        int idx = tid * 10 + i;
        if (idx < N_NODES) {
            int v = base + vals[i];
            offsets[idx] = v;
            cursor[idx] = v;
        }
    }
    if (tid == 1023) offsets[N_NODES] = wbase + inc;
}

__global__ __launch_bounds__(256) void scatter_kernel(const int* __restrict__ eidx,
                                                      int* __restrict__ cursor,
                                                      int* __restrict__ edge_order,
                                                      int* __restrict__ edge_src) {
    int i = blockIdx.x * blockDim.x + threadIdx.x;
    if (i < N_EDGES) {
        int s = eidx[i];
        int pos = atomicAdd(&cursor[s], 1);
        edge_order[pos] = i;
        edge_src[pos] = s;
    }
}

// ---------------- edge MFMA kernel: 16 sorted edges/block ----------------
// Payload loads (xsp/rsh for all 16 edges) are issued BEFORE phase A so the
// HBM latency hides under the MFMA + epilogue; consumed after the barrier.
__global__ __launch_bounds__(256, 4) void edge_mfma(
    const float* __restrict__ xsp,
    const float* __restrict__ rbf, const float* __restrict__ fcut,
    const float* __restrict__ rsh, const int* __restrict__ eidx,
    const unsigned short* __restrict__ bfrag, const float* __restrict__ br,
    const float* __restrict__ so,
    const int* __restrict__ edge_order, const int* __restrict__ edge_src,
    float* __restrict__ out_scalar, float* __restrict__ out_sph)
{
    __shared__ unsigned int   pair_s[EB][IRP];    // 14.9 KB (odd stride)
    __shared__ unsigned short scal_s[EB][SCP];    // 4.4 KB (69-word odd stride)
    __shared__ int   e_s[EB];
    __shared__ int   src_s[EB];
    __shared__ int   dst_s[EB];
    __shared__ float fc_s[EB];

    const int t = threadIdx.x;
    const int base = blockIdx.x * EB;
    const int lane = t & 63, w = t >> 6;

    // ---- A-fragment: direct global load (lane l: edge row l&15, k=(l>>4)*8+j) ----
    const int m_row = lane & 15;
    const int kb = (lane >> 4) * 8;
    const int e_row = edge_order[base + m_row];
    short8v a0;
    {
        const float* rrow = rbf + (size_t)e_row * NUM_BASIS;
        #pragma unroll
        for (int j = 0; j < 8; ++j) {
            const int k = kb + j;
            a0[j] = (k < NUM_BASIS) ? (short)f2bf(rrow[k]) : (short)0;
        }
    }

    // ---- stage meta ----
    if (t < EB) {
        int pos = base + t;
        int e = edge_order[pos];
        e_s[t]   = e;
        src_s[t] = edge_src[pos];
        dst_s[t] = eidx[N_EDGES + e];
        fc_s[t]  = fcut[e];
    }
    __syncthreads();

    // ---- issue ALL phase-B payload loads now (64/thread-ish, hide under phase A) ----
    float xv1[EB], rv1[EB], xv2[EB], rv2[EB];
    #pragma unroll
    for (int le = 0; le < EB; ++le) {
        const int dst = dst_s[le];
        const int eg  = e_s[le];
        const float* xr = xsp + (size_t)dst * SPH_DIM;
        const float* rr = rsh + (size_t)eg  * SPH_DIM;
        xv1[le] = xr[t];
        rv1[le] = rr[t];
        if (t < 224) { xv2[le] = xr[256 + t]; rv2[le] = rr[256 + t]; }
        else         { xv2[le] = 0.f;         rv2[le] = 0.f; }
    }

    // ---- phase A: 9 N-tiles per wave ----
    {
        const int rbase = (lane >> 4) * 4;
        int   dA[4];
        float fA[4];
        #pragma unroll
        for (int r = 0; r < 4; ++r) { dA[r] = dst_s[rbase + r]; fA[r] = fc_s[rbase + r]; }
        #pragma unroll
        for (int i = 0; i < NT / 4; ++i) {
            const int nt = w * (NT / 4) + i;
            const short8v bf = *(const short8v*)(bfrag + (size_t)(nt * 64 + lane) * 8);
            f32x4 c0 = {0.f, 0.f, 0.f, 0.f};
            c0 = __builtin_amdgcn_mfma_f32_16x16x32_bf16(a0, bf, c0, 0, 0, 0);
            const int col = nt * 16 + (lane & 15);
            const float brc = br[col];
            #pragma unroll
            for (int r = 0; r < 4; ++r) {
                const int row = rbase + r;
                const float v = (c0[r] + brc) * fA[r] * so[(size_t)dA[r] * HIDDEN + col];
                const unsigned short hv = f2bf(v);
                if (col < NUM_IRREPS) {
                    ((unsigned short*)&pair_s[row][col])[0] = hv;              // state (lo)
                } else if (col < 2 * NUM_IRREPS) {
                    ((unsigned short*)&pair_s[row][col - NUM_IRREPS])[1] = hv; // edge (hi)
                } else {
                    scal_s[row][col - 2 * NUM_IRREPS] = hv;
                }
            }
        }
    }
    __syncthreads();

    // ---- phase B: consume from registers, segmented accumulate ----
    const int g1i = (t < 128) ? t : (128 + (t - 128) / 3);
    const int g2i = (t < 64) ? (128 + (128 + t) / 3) : (192 + (t - 64) / 5);

    float accS = 0.f, accD1 = 0.f, accD2 = 0.f;
    int cur_src = src_s[0];

    #pragma unroll
    for (int le = 0; le < EB; ++le) {
        const int s = src_s[le];
        if (s != cur_src) {   // block-uniform branch
            atomicAdd(&out_sph[(size_t)cur_src * SPH_DIM + t], accD1);
            if (t < 224) atomicAdd(&out_sph[(size_t)cur_src * SPH_DIM + 256 + t], accD2);
            if (t < 128) atomicAdd(&out_scalar[(size_t)cur_src * NODE_DIM + t], accS);
            accD1 = accD2 = accS = 0.f;
            cur_src = s;
        }
        const unsigned int p1 = pair_s[le][g1i];
        accD1 = fmaf(xv1[le], bf2f((unsigned short)(p1 & 0xffffu)),
                fmaf(rv1[le], bf2f((unsigned short)(p1 >> 16)), accD1));
        if (t < 224) {
            const unsigned int p2 = pair_s[le][g2i];
            accD2 = fmaf(xv2[le], bf2f((unsigned short)(p2 & 0xffffu)),
                    fmaf(rv2[le], bf2f((unsigned short)(p2 >> 16)), accD2));
        }
        if (t < 128) accS += bf2f(scal_s[le][t]);
    }
    atomicAdd(&out_sph[(size_t)cur_src * SPH_DIM + t], accD1);
    if (t < 224) atomicAdd(&out_sph[(size_t)cur_src * SPH_DIM + 256 + t], accD2);
    if (t < 128) atomicAdd(&out_scalar[(size_t)cur_src * NODE_DIM + t], accS);
}

extern "C" void kernel_launch(void* const* d_in, const int* in_sizes, int n_in,
                              void* d_out, int out_size, void* d_ws, size_t ws_size,
                              hipStream_t stream) {
    const float* x_scalar    = (const float*)d_in[0];
    const float* x_spherical = (const float*)d_in[1];
    const float* rbf         = (const float*)d_in[2];
    const float* fcut        = (const float*)d_in[3];
    const float* rsh         = (const float*)d_in[4];
    const int*   eidx        = (const int*)d_in[5];
    const float* W1          = (const float*)d_in[6];
    const float* b1          = (const float*)d_in[7];
    const float* W2          = (const float*)d_in[8];
    const float* b2          = (const float*)d_in[9];
    const float* Wr          = (const float*)d_in[10];
    const float* br          = (const float*)d_in[11];

    float* out        = (float*)d_out;
    float* out_scalar = out;                                   // (N_NODES, 128)
    float* out_sph    = out + (size_t)N_NODES * NODE_DIM;      // (N_NODES, 480)

    // workspace layout
    float* scalar_out = (float*)d_ws;                          // 10000*576 floats
    int*   counts     = (int*)(scalar_out + (size_t)N_NODES * HIDDEN);   // 10000
    int*   offsets    = counts + N_NODES;                      // 10001
    int*   cursor     = offsets + N_NODES + 1;                 // 10000
    int*   edge_order = cursor + N_NODES;                      // 160000
    int*   edge_src   = edge_order + N_EDGES;                  // 160000
    unsigned short* bfrag = (unsigned short*)((((uintptr_t)(edge_src + N_EDGES)) + 15) & ~(uintptr_t)15);  // 36*64*8 bf16

    hipMemsetAsync(counts, 0, N_NODES * sizeof(int), stream);
    prep_kernel<<<2048, 256, 0, stream>>>(x_scalar, x_spherical, out, eidx, counts, Wr, bfrag);
    scan_kernel<<<1, 1024, 0, stream>>>(counts, offsets, cursor);
    scatter_kernel<<<(N_EDGES + 255) / 256, 256, 0, stream>>>(eidx, cursor, edge_order, edge_src);
    node_mlp<<<(N_NODES + NPB - 1) / NPB, 128, 0, stream>>>(x_scalar, W1, b1, W2, b2, scalar_out);
    edge_mfma<<<N_EDGES / EB, 256, 0, stream>>>(x_spherical, rbf, fcut, rsh, eidx,
                                                bfrag, br, scalar_out, edge_order, edge_src,
                                                out_scalar, out_sph);
}

// Round 12
// 356.343 us; speedup vs baseline: 1.1076x; 1.1076x over previous
//
#include <hip/hip_runtime.h>

#define NODE_DIM 128
#define NUM_IRREPS 224
#define SPH_DIM 480
#define HIDDEN 576   // NODE_DIM + 2*NUM_IRREPS
#define NUM_BASIS 20
#define N_NODES 10000
#define N_EDGES 160000
#define NPB 8        // nodes per block in node MLP
#define EB 16        // edges per window (block)
#define NT 36        // N-tiles (576/16)
#define IRP 233      // pair row stride in words (odd)
#define SCP 138      // scal row stride in shorts (69 words, odd)

typedef __attribute__((ext_vector_type(8))) short short8v;   // 8 bf16
typedef __attribute__((ext_vector_type(4))) float f32x4;

__device__ __forceinline__ unsigned short f2bf(float f) {
    unsigned int u = __builtin_bit_cast(unsigned int, f);
    u = (u + 0x7fff + ((u >> 16) & 1)) >> 16;   // RNE
    return (unsigned short)u;
}
__device__ __forceinline__ float bf2f(unsigned short h) {
    unsigned int u = ((unsigned int)h) << 16;
    return __builtin_bit_cast(float, u);
}

// ---------------- fused prep: copy x->out, histogram, bfrag, xpair table ----------------
// counts must be zeroed beforehand (hipMemsetAsync).
__global__ __launch_bounds__(256) void prep_kernel(
    const float* __restrict__ xs, const float* __restrict__ xsp,
    float* __restrict__ out,
    const int* __restrict__ eidx, int* __restrict__ counts,
    const float* __restrict__ Wr, unsigned short* __restrict__ bfrag,
    unsigned int* __restrict__ xpair) {
    const int stride = gridDim.x * blockDim.x;
    const int gt = blockIdx.x * blockDim.x + threadIdx.x;
    // copy outputs' base
    for (int i = gt; i < N_NODES * NODE_DIM; i += stride) out[i] = xs[i];
    float* o2 = out + (size_t)N_NODES * NODE_DIM;
    for (int i = gt; i < N_NODES * SPH_DIM; i += stride) o2[i] = xsp[i];
    // bf16 paired xsp table: xpair[n*256+t] = {xsp[n][t] | xsp[n][256+t]<<16}
    for (int i = gt; i < N_NODES * 256; i += stride) {
        const int n = i >> 8, t = i & 255;
        const float* xr = xsp + (size_t)n * SPH_DIM;
        unsigned int lo = f2bf(xr[t]);
        unsigned int hi = (t < NUM_IRREPS) ? f2bf(xr[256 + t]) : 0u;
        xpair[i] = lo | (hi << 16);
    }
    // histogram by src
    if (gt < N_EDGES) atomicAdd(&counts[eidx[gt]], 1);
    // B-frag prep (last block): lane l holds col (l&15), k=(l>>4)*8+j
    if (blockIdx.x == gridDim.x - 1) {
        for (int idx = threadIdx.x; idx < NT * 64; idx += 256) {
            const int nt = idx >> 6, l = idx & 63;
            const int col = nt * 16 + (l & 15);
            const int kb = (l >> 4) * 8;
            #pragma unroll
            for (int j = 0; j < 8; ++j) {
                const int k = kb + j;
                bfrag[(size_t)idx * 8 + j] = (k < NUM_BASIS) ? f2bf(Wr[k * HIDDEN + col]) : (unsigned short)0;
            }
        }
    }
}

// ---------------- node MLP: so_bf = bf16( silu(x@W1+b1)@W2+b2 ) ----------------
__global__ __launch_bounds__(128) void node_mlp(
    const float* __restrict__ x,
    const float* __restrict__ W1, const float* __restrict__ b1,
    const float* __restrict__ W2, const float* __restrict__ b2,
    unsigned short* __restrict__ so_bf) {
    __shared__ float xs[NPB][NODE_DIM];
    __shared__ float hs[NPB][NODE_DIM];
    const int tid = threadIdx.x;
    const int n0 = blockIdx.x * NPB;

    #pragma unroll
    for (int n = 0; n < NPB; ++n) {
        int node = n0 + n;
        xs[n][tid] = (node < N_NODES) ? x[(size_t)node * NODE_DIM + tid] : 0.f;
    }
    __syncthreads();

    float acc[NPB];
    #pragma unroll
    for (int n = 0; n < NPB; ++n) acc[n] = b1[tid];
    for (int k = 0; k < NODE_DIM; ++k) {
        float w = W1[k * NODE_DIM + tid];
        #pragma unroll
        for (int n = 0; n < NPB; ++n) acc[n] = fmaf(xs[n][k], w, acc[n]);
    }
    #pragma unroll
    for (int n = 0; n < NPB; ++n) {
        float v = acc[n];
        hs[n][tid] = v / (1.f + __expf(-v));
    }
    __syncthreads();

    for (int j = tid; j < HIDDEN; j += 128) {
        float a2[NPB];
        #pragma unroll
        for (int n = 0; n < NPB; ++n) a2[n] = b2[j];
        for (int k = 0; k < NODE_DIM; ++k) {
            float w = W2[k * HIDDEN + j];
            #pragma unroll
            for (int n = 0; n < NPB; ++n) a2[n] = fmaf(hs[n][k], w, a2[n]);
        }
        #pragma unroll
        for (int n = 0; n < NPB; ++n) {
            int node = n0 + n;
            if (node < N_NODES) so_bf[(size_t)node * HIDDEN + j] = f2bf(a2[n]);
        }
    }
}

// ---------------- CSR scan / scatter ----------------
__global__ __launch_bounds__(1024) void scan_kernel(const int* __restrict__ counts,
                                                    int* __restrict__ offsets,
                                                    int* __restrict__ cursor) {
    __shared__ int wsum[16];
    const int tid = threadIdx.x;
    int vals[10];
    int run = 0;
    #pragma unroll
    for (int i = 0; i < 10; ++i) {
        int idx = tid * 10 + i;
        int c = (idx < N_NODES) ? counts[idx] : 0;
        vals[i] = run;
        run += c;
    }
    const int lane = tid & 63, w = tid >> 6;
    int inc = run;
    #pragma unroll
    for (int off = 1; off < 64; off <<= 1) {
        int v = __shfl_up(inc, off);
        if (lane >= off) inc += v;
    }
    if (lane == 63) wsum[w] = inc;
    __syncthreads();
    if (w == 0) {
        int v = (lane < 16) ? wsum[lane] : 0;
        #pragma unroll
        for (int off = 1; off < 16; off <<= 1) {
            int u = __shfl_up(v, off);
            if (lane >= off) v += u;
        }
        if (lane < 16) wsum[lane] = v;
    }
    __syncthreads();
    const int wbase = (w > 0) ? wsum[w - 1] : 0;
    const int base = wbase + inc - run;   // exclusive prefix
    #pragma unroll
    for (int i = 0; i < 10; ++i) {
        int idx = tid * 10 + i;
        if (idx < N_NODES) {
            int v = base + vals[i];
            offsets[idx] = v;
            cursor[idx] = v;
        }
    }
    if (tid == 1023) offsets[N_NODES] = wbase + inc;
}

__global__ __launch_bounds__(256) void scatter_kernel(const int* __restrict__ eidx,
                                                      int* __restrict__ cursor,
                                                      int* __restrict__ edge_order,
                                                      int* __restrict__ edge_src) {
    int i = blockIdx.x * blockDim.x + threadIdx.x;
    if (i < N_EDGES) {
        int s = eidx[i];
        int pos = atomicAdd(&cursor[s], 1);
        edge_order[pos] = i;
        edge_src[pos] = s;
    }
}

// ---------------- edge MFMA kernel: 16 sorted edges/block ----------------
// Phase A: filter GEMM on matrix cores; epilogue uses bf16 so table.
// Phase B: xsp via pre-paired bf16 u32 gather (1 instr/edge), rsh fp32.
__global__ __launch_bounds__(256, 8) void edge_mfma(
    const unsigned int* __restrict__ xpair,
    const float* __restrict__ rbf, const float* __restrict__ fcut,
    const float* __restrict__ rsh, const int* __restrict__ eidx,
    const unsigned short* __restrict__ bfrag, const float* __restrict__ br,
    const unsigned short* __restrict__ so_bf,
    const int* __restrict__ edge_order, const int* __restrict__ edge_src,
    float* __restrict__ out_scalar, float* __restrict__ out_sph)
{
    __shared__ unsigned int   pair_s[EB][IRP];    // 14.9 KB
    __shared__ unsigned short scal_s[EB][SCP];    // 4.4 KB
    __shared__ int   e_s[EB];
    __shared__ int   src_s[EB];
    __shared__ int   dst_s[EB];
    __shared__ float fc_s[EB];

    const int t = threadIdx.x;
    const int base = blockIdx.x * EB;
    const int lane = t & 63, w = t >> 6;

    // ---- A-fragment: direct global load (lane l: edge row l&15, k=(l>>4)*8+j) ----
    const int m_row = lane & 15;
    const int kb = (lane >> 4) * 8;
    const int e_row = edge_order[base + m_row];
    short8v a0;
    {
        const float* rrow = rbf + (size_t)e_row * NUM_BASIS;
        #pragma unroll
        for (int j = 0; j < 8; ++j) {
            const int k = kb + j;
            a0[j] = (k < NUM_BASIS) ? (short)f2bf(rrow[k]) : (short)0;
        }
    }

    // ---- stage meta ----
    if (t < EB) {
        int pos = base + t;
        int e = edge_order[pos];
        e_s[t]   = e;
        src_s[t] = edge_src[pos];
        dst_s[t] = eidx[N_EDGES + e];
        fc_s[t]  = fcut[e];
    }
    __syncthreads();

    // ---- phase A: 9 N-tiles per wave ----
    {
        const int rbase = (lane >> 4) * 4;
        int   dA[4];
        float fA[4];
        #pragma unroll
        for (int r = 0; r < 4; ++r) { dA[r] = dst_s[rbase + r]; fA[r] = fc_s[rbase + r]; }
        #pragma unroll
        for (int i = 0; i < NT / 4; ++i) {
            const int nt = w * (NT / 4) + i;
            const short8v bf = *(const short8v*)(bfrag + (size_t)(nt * 64 + lane) * 8);
            f32x4 c0 = {0.f, 0.f, 0.f, 0.f};
            c0 = __builtin_amdgcn_mfma_f32_16x16x32_bf16(a0, bf, c0, 0, 0, 0);
            const int col = nt * 16 + (lane & 15);
            const float brc = br[col];
            #pragma unroll
            for (int r = 0; r < 4; ++r) {
                const int row = rbase + r;
                const float sov = bf2f(so_bf[(size_t)dA[r] * HIDDEN + col]);
                const float v = (c0[r] + brc) * fA[r] * sov;
                const unsigned short hv = f2bf(v);
                if (col < NUM_IRREPS) {
                    ((unsigned short*)&pair_s[row][col])[0] = hv;              // state (lo)
                } else if (col < 2 * NUM_IRREPS) {
                    ((unsigned short*)&pair_s[row][col - NUM_IRREPS])[1] = hv; // edge (hi)
                } else {
                    scal_s[row][col - 2 * NUM_IRREPS] = hv;
                }
            }
        }
    }
    __syncthreads();

    // ---- phase B: paired-gather consume, segmented accumulate ----
    const int g1i = (t < 128) ? t : (128 + (t - 128) / 3);
    const int g2i = (t < 64) ? (128 + (128 + t) / 3) : (192 + (t - 64) / 5);

    float accS = 0.f, accD1 = 0.f, accD2 = 0.f;
    int cur_src = src_s[0];

    #pragma unroll 8
    for (int le = 0; le < EB; ++le) {
        const int s = src_s[le];
        if (s != cur_src) {   // block-uniform branch
            atomicAdd(&out_sph[(size_t)cur_src * SPH_DIM + t], accD1);
            if (t < 224) atomicAdd(&out_sph[(size_t)cur_src * SPH_DIM + 256 + t], accD2);
            if (t < 128) atomicAdd(&out_scalar[(size_t)cur_src * NODE_DIM + t], accS);
            accD1 = accD2 = accS = 0.f;
            cur_src = s;
        }
        const int dst = dst_s[le];
        const int eg  = e_s[le];
        const unsigned int xp = xpair[(size_t)dst * 256 + t];   // {x[t], x[256+t]} bf16
        const float rv1 = rsh[(size_t)eg * SPH_DIM + t];
        const unsigned int p1 = pair_s[le][g1i];
        accD1 = fmaf(bf2f((unsigned short)(xp & 0xffffu)), bf2f((unsigned short)(p1 & 0xffffu)),
                fmaf(rv1, bf2f((unsigned short)(p1 >> 16)), accD1));
        if (t < 224) {
            const float rv2 = rsh[(size_t)eg * SPH_DIM + 256 + t];
            const unsigned int p2 = pair_s[le][g2i];
            accD2 = fmaf(bf2f((unsigned short)(xp >> 16)), bf2f((unsigned short)(p2 & 0xffffu)),
                    fmaf(rv2, bf2f((unsigned short)(p2 >> 16)), accD2));
        }
        if (t < 128) accS += bf2f(scal_s[le][t]);
    }
    atomicAdd(&out_sph[(size_t)cur_src * SPH_DIM + t], accD1);
    if (t < 224) atomicAdd(&out_sph[(size_t)cur_src * SPH_DIM + 256 + t], accD2);
    if (t < 128) atomicAdd(&out_scalar[(size_t)cur_src * NODE_DIM + t], accS);
}

extern "C" void kernel_launch(void* const* d_in, const int* in_sizes, int n_in,
                              void* d_out, int out_size, void* d_ws, size_t ws_size,
                              hipStream_t stream) {
    const float* x_scalar    = (const float*)d_in[0];
    const float* x_spherical = (const float*)d_in[1];
    const float* rbf         = (const float*)d_in[2];
    const float* fcut        = (const float*)d_in[3];
    const float* rsh         = (const float*)d_in[4];
    const int*   eidx        = (const int*)d_in[5];
    const float* W1          = (const float*)d_in[6];
    const float* b1          = (const float*)d_in[7];
    const float* W2          = (const float*)d_in[8];
    const float* b2          = (const float*)d_in[9];
    const float* Wr          = (const float*)d_in[10];
    const float* br          = (const float*)d_in[11];

    float* out        = (float*)d_out;
    float* out_scalar = out;                                   // (N_NODES, 128)
    float* out_sph    = out + (size_t)N_NODES * NODE_DIM;      // (N_NODES, 480)

    // workspace layout
    unsigned short* so_bf   = (unsigned short*)d_ws;           // 10000*576 bf16 (11.5 MB)
    unsigned int*   xpair   = (unsigned int*)(so_bf + (size_t)N_NODES * HIDDEN);  // 10000*256 u32 (10.2 MB)
    int*   counts     = (int*)(xpair + (size_t)N_NODES * 256); // 10000
    int*   offsets    = counts + N_NODES;                      // 10001
    int*   cursor     = offsets + N_NODES + 1;                 // 10000
    int*   edge_order = cursor + N_NODES;                      // 160000
    int*   edge_src   = edge_order + N_EDGES;                  // 160000
    unsigned short* bfrag = (unsigned short*)((((uintptr_t)(edge_src + N_EDGES)) + 15) & ~(uintptr_t)15);  // 36*64*8 bf16

    hipMemsetAsync(counts, 0, N_NODES * sizeof(int), stream);
    prep_kernel<<<2048, 256, 0, stream>>>(x_scalar, x_spherical, out, eidx, counts, Wr, bfrag, xpair);
    scan_kernel<<<1, 1024, 0, stream>>>(counts, offsets, cursor);
    scatter_kernel<<<(N_EDGES + 255) / 256, 256, 0, stream>>>(eidx, cursor, edge_order, edge_src);
    node_mlp<<<(N_NODES + NPB - 1) / NPB, 128, 0, stream>>>(x_scalar, W1, b1, W2, b2, so_bf);
    edge_mfma<<<N_EDGES / EB, 256, 0, stream>>>(xpair, rbf, fcut, rsh, eidx,
                                                bfrag, br, so_bf, edge_order, edge_src,
                                                out_scalar, out_sph);
}

// Round 13
// 285.138 us; speedup vs baseline: 1.3842x; 1.2497x over previous
//
#include <hip/hip_runtime.h>

#define NODE_DIM 128
#define NUM_IRREPS 224
#define SPH_DIM 480
#define HIDDEN 576   // NODE_DIM + 2*NUM_IRREPS
#define NUM_BASIS 20
#define N_NODES 10000
#define N_EDGES 160000
#define NPB 4        // nodes per block in fused MLP
#define EB 16        // edges per window (block)
#define NT 36        // N-tiles (576/16)
#define IRP 233      // pair row stride in words (odd)
#define SCP 138      // scal row stride in shorts (69 words, odd)
#define PREP_BLOCKS 2048
#define MLP_BLOCKS ((N_NODES + NPB - 1) / NPB)

typedef __attribute__((ext_vector_type(8))) short short8v;   // 8 bf16
typedef __attribute__((ext_vector_type(4))) float f32x4;

__device__ __forceinline__ unsigned short f2bf(float f) {
    unsigned int u = __builtin_bit_cast(unsigned int, f);
    u = (u + 0x7fff + ((u >> 16) & 1)) >> 16;   // RNE
    return (unsigned short)u;
}
__device__ __forceinline__ float bf2f(unsigned short h) {
    unsigned int u = ((unsigned int)h) << 16;
    return __builtin_bit_cast(float, u);
}

// ---------------- fused prep + node MLP (disjoint block ranges, concurrent) ----------------
// blocks [0, PREP_BLOCKS): copy x->out, histogram, (last) bfrag prep
// blocks [PREP_BLOCKS, PREP_BLOCKS+MLP_BLOCKS): node MLP -> so_bf
__global__ __launch_bounds__(256) void prep_mlp_kernel(
    const float* __restrict__ xs, const float* __restrict__ xsp,
    float* __restrict__ out,
    const int* __restrict__ eidx, int* __restrict__ counts,
    const float* __restrict__ Wr, unsigned short* __restrict__ bfrag,
    const float* __restrict__ W1, const float* __restrict__ b1,
    const float* __restrict__ W2, const float* __restrict__ b2,
    unsigned short* __restrict__ so_bf)
{
    const int t = threadIdx.x;
    if (blockIdx.x < PREP_BLOCKS) {
        const int stride = PREP_BLOCKS * 256;
        const int gt = blockIdx.x * 256 + t;
        for (int i = gt; i < N_NODES * NODE_DIM; i += stride) out[i] = xs[i];
        float* o2 = out + (size_t)N_NODES * NODE_DIM;
        for (int i = gt; i < N_NODES * SPH_DIM; i += stride) o2[i] = xsp[i];
        if (gt < N_EDGES) atomicAdd(&counts[eidx[gt]], 1);
        if (blockIdx.x == PREP_BLOCKS - 1) {
            for (int idx = t; idx < NT * 64; idx += 256) {
                const int nt = idx >> 6, l = idx & 63;
                const int col = nt * 16 + (l & 15);
                const int kb = (l >> 4) * 8;
                #pragma unroll
                for (int j = 0; j < 8; ++j) {
                    const int k = kb + j;
                    bfrag[(size_t)idx * 8 + j] = (k < NUM_BASIS) ? f2bf(Wr[k * HIDDEN + col]) : (unsigned short)0;
                }
            }
        }
        return;
    }
    // ---- node MLP: 256 threads, 4 nodes/block ----
    __shared__ float xsm[NPB][NODE_DIM];
    __shared__ float hsm[NPB][NODE_DIM];
    const int n0 = (blockIdx.x - PREP_BLOCKS) * NPB;
    const int half = t >> 7;          // 0: nodes 0,1   1: nodes 2,3
    const int tc = t & 127;

    #pragma unroll
    for (int i = 0; i < 2; ++i) {
        const int nn = 2 * half + i;
        const int node = n0 + nn;
        xsm[nn][tc] = (node < N_NODES) ? xs[(size_t)node * NODE_DIM + tc] : 0.f;
    }
    __syncthreads();

    float acc[2] = {b1[tc], b1[tc]};
    for (int k = 0; k < NODE_DIM; ++k) {
        const float w = W1[k * NODE_DIM + tc];
        #pragma unroll
        for (int i = 0; i < 2; ++i) acc[i] = fmaf(xsm[2 * half + i][k], w, acc[i]);
    }
    #pragma unroll
    for (int i = 0; i < 2; ++i) {
        const float v = acc[i];
        hsm[2 * half + i][tc] = v / (1.f + __expf(-v));
    }
    __syncthreads();

    for (int j = t; j < HIDDEN; j += 256) {
        float a2[NPB];
        #pragma unroll
        for (int n = 0; n < NPB; ++n) a2[n] = b2[j];
        for (int k = 0; k < NODE_DIM; ++k) {
            const float w = W2[k * HIDDEN + j];
            #pragma unroll
            for (int n = 0; n < NPB; ++n) a2[n] = fmaf(hsm[n][k], w, a2[n]);
        }
        #pragma unroll
        for (int n = 0; n < NPB; ++n) {
            const int node = n0 + n;
            if (node < N_NODES) so_bf[(size_t)node * HIDDEN + j] = f2bf(a2[n]);
        }
    }
}

// ---------------- CSR scan / scatter ----------------
__global__ __launch_bounds__(1024) void scan_kernel(const int* __restrict__ counts,
                                                    int* __restrict__ offsets,
                                                    int* __restrict__ cursor) {
    __shared__ int wsum[16];
    const int tid = threadIdx.x;
    int vals[10];
    int run = 0;
    #pragma unroll
    for (int i = 0; i < 10; ++i) {
        int idx = tid * 10 + i;
        int c = (idx < N_NODES) ? counts[idx] : 0;
        vals[i] = run;
        run += c;
    }
    const int lane = tid & 63, w = tid >> 6;
    int inc = run;
    #pragma unroll
    for (int off = 1; off < 64; off <<= 1) {
        int v = __shfl_up(inc, off);
        if (lane >= off) inc += v;
    }
    if (lane == 63) wsum[w] = inc;
    __syncthreads();
    if (w == 0) {
        int v = (lane < 16) ? wsum[lane] : 0;
        #pragma unroll
        for (int off = 1; off < 16; off <<= 1) {
            int u = __shfl_up(v, off);
            if (lane >= off) v += u;
        }
        if (lane < 16) wsum[lane] = v;
    }
    __syncthreads();
    const int wbase = (w > 0) ? wsum[w - 1] : 0;
    const int base = wbase + inc - run;   // exclusive prefix
    #pragma unroll
    for (int i = 0; i < 10; ++i) {
        int idx = tid * 10 + i;
        if (idx < N_NODES) {
            int v = base + vals[i];
            offsets[idx] = v;
            cursor[idx] = v;
        }
    }
    if (tid == 1023) offsets[N_NODES] = wbase + inc;
}

__global__ __launch_bounds__(256) void scatter_kernel(const int* __restrict__ eidx,
                                                      int* __restrict__ cursor,
                                                      int* __restrict__ edge_order,
                                                      int* __restrict__ edge_src) {
    int i = blockIdx.x * blockDim.x + threadIdx.x;
    if (i < N_EDGES) {
        int s = eidx[i];
        int pos = atomicAdd(&cursor[s], 1);
        edge_order[pos] = i;
        edge_src[pos] = s;
    }
}

__device__ __forceinline__ int gate_of(int d) {
    return (d < 128) ? d : (d < 320) ? (128 + (d - 128) / 3) : (192 + (d - 320) / 5);
}

// ---------------- edge MFMA kernel: 16 sorted edges/block ----------------
// Phase A: filter GEMM on matrix cores; epilogue gathers bf16 so.
// Phase B: thread t<240 owns d=2t,2t+1 -> float2 xsp/rsh loads (fp32 inputs),
//   2-deep named-scalar prefetch; segmented atomic flush on src change.
__global__ __launch_bounds__(256, 4) void edge_mfma(
    const float* __restrict__ xsp,
    const float* __restrict__ rbf, const float* __restrict__ fcut,
    const float* __restrict__ rsh, const int* __restrict__ eidx,
    const unsigned short* __restrict__ bfrag, const float* __restrict__ br,
    const unsigned short* __restrict__ so_bf,
    const int* __restrict__ edge_order, const int* __restrict__ edge_src,
    float* __restrict__ out_scalar, float* __restrict__ out_sph)
{
    __shared__ unsigned int   pair_s[EB][IRP];    // 14.9 KB
    __shared__ unsigned short scal_s[EB][SCP];    // 4.4 KB
    __shared__ int   e_s[EB];
    __shared__ int   src_s[EB];
    __shared__ int   dst_s[EB];
    __shared__ float fc_s[EB];

    const int t = threadIdx.x;
    const int base = blockIdx.x * EB;
    const int lane = t & 63, w = t >> 6;

    // ---- A-fragment: direct global load (lane l: edge row l&15, k=(l>>4)*8+j) ----
    const int m_row = lane & 15;
    const int kb = (lane >> 4) * 8;
    const int e_row = edge_order[base + m_row];
    short8v a0;
    {
        const float* rrow = rbf + (size_t)e_row * NUM_BASIS;
        #pragma unroll
        for (int j = 0; j < 8; ++j) {
            const int k = kb + j;
            a0[j] = (k < NUM_BASIS) ? (short)f2bf(rrow[k]) : (short)0;
        }
    }

    // ---- stage meta ----
    if (t < EB) {
        int pos = base + t;
        int e = edge_order[pos];
        e_s[t]   = e;
        src_s[t] = edge_src[pos];
        dst_s[t] = eidx[N_EDGES + e];
        fc_s[t]  = fcut[e];
    }
    __syncthreads();

    // ---- phase A: 9 N-tiles per wave ----
    {
        const int rbase = (lane >> 4) * 4;
        int   dA[4];
        float fA[4];
        #pragma unroll
        for (int r = 0; r < 4; ++r) { dA[r] = dst_s[rbase + r]; fA[r] = fc_s[rbase + r]; }
        #pragma unroll
        for (int i = 0; i < NT / 4; ++i) {
            const int nt = w * (NT / 4) + i;
            const short8v bf = *(const short8v*)(bfrag + (size_t)(nt * 64 + lane) * 8);
            f32x4 c0 = {0.f, 0.f, 0.f, 0.f};
            c0 = __builtin_amdgcn_mfma_f32_16x16x32_bf16(a0, bf, c0, 0, 0, 0);
            const int col = nt * 16 + (lane & 15);
            const float brc = br[col];
            #pragma unroll
            for (int r = 0; r < 4; ++r) {
                const int row = rbase + r;
                const float sov = bf2f(so_bf[(size_t)dA[r] * HIDDEN + col]);
                const float v = (c0[r] + brc) * fA[r] * sov;
                const unsigned short hv = f2bf(v);
                if (col < NUM_IRREPS) {
                    ((unsigned short*)&pair_s[row][col])[0] = hv;              // state (lo)
                } else if (col < 2 * NUM_IRREPS) {
                    ((unsigned short*)&pair_s[row][col - NUM_IRREPS])[1] = hv; // edge (hi)
                } else {
                    scal_s[row][col - 2 * NUM_IRREPS] = hv;
                }
            }
        }
    }
    __syncthreads();

    // ---- phase B: float2 consume, 2-deep prefetch, segmented accumulate ----
    const bool sphOn = (t < 240);
    const int d0 = 2 * t;
    const int g0 = sphOn ? gate_of(d0) : 0;
    const int g1 = sphOn ? gate_of(d0 + 1) : 0;

    float accS = 0.f, accD0 = 0.f, accD1 = 0.f;
    int cur_src = src_s[0];

    float xq0, xq1, rq0, rq1;           // current payload (named scalars)
    if (sphOn) {
        const float2 xv = *(const float2*)(xsp + (size_t)dst_s[0] * SPH_DIM + d0);
        const float2 rv = *(const float2*)(rsh + (size_t)e_s[0]  * SPH_DIM + d0);
        xq0 = xv.x; xq1 = xv.y; rq0 = rv.x; rq1 = rv.y;
    }

    #pragma unroll
    for (int le = 0; le < EB; ++le) {
        // prefetch next edge payload
        float nx0, nx1, nr0, nr1;
        if (sphOn && le + 1 < EB) {
            const float2 xv = *(const float2*)(xsp + (size_t)dst_s[le + 1] * SPH_DIM + d0);
            const float2 rv = *(const float2*)(rsh + (size_t)e_s[le + 1]  * SPH_DIM + d0);
            nx0 = xv.x; nx1 = xv.y; nr0 = rv.x; nr1 = rv.y;
        }
        const int s = src_s[le];
        if (s != cur_src) {   // block-uniform branch
            if (sphOn) {
                atomicAdd(&out_sph[(size_t)cur_src * SPH_DIM + d0],     accD0);
                atomicAdd(&out_sph[(size_t)cur_src * SPH_DIM + d0 + 1], accD1);
            }
            if (t < 128) atomicAdd(&out_scalar[(size_t)cur_src * NODE_DIM + t], accS);
            accD0 = accD1 = accS = 0.f;
            cur_src = s;
        }
        if (sphOn) {
            const unsigned int p0 = pair_s[le][g0];
            const unsigned int p1 = pair_s[le][g1];
            accD0 = fmaf(xq0, bf2f((unsigned short)(p0 & 0xffffu)),
                    fmaf(rq0, bf2f((unsigned short)(p0 >> 16)), accD0));
            accD1 = fmaf(xq1, bf2f((unsigned short)(p1 & 0xffffu)),
                    fmaf(rq1, bf2f((unsigned short)(p1 >> 16)), accD1));
        }
        if (t < 128) accS += bf2f(scal_s[le][t]);
        if (sphOn && le + 1 < EB) { xq0 = nx0; xq1 = nx1; rq0 = nr0; rq1 = nr1; }
    }
    if (sphOn) {
        atomicAdd(&out_sph[(size_t)cur_src * SPH_DIM + d0],     accD0);
        atomicAdd(&out_sph[(size_t)cur_src * SPH_DIM + d0 + 1], accD1);
    }
    if (t < 128) atomicAdd(&out_scalar[(size_t)cur_src * NODE_DIM + t], accS);
}

extern "C" void kernel_launch(void* const* d_in, const int* in_sizes, int n_in,
                              void* d_out, int out_size, void* d_ws, size_t ws_size,
                              hipStream_t stream) {
    const float* x_scalar    = (const float*)d_in[0];
    const float* x_spherical = (const float*)d_in[1];
    const float* rbf         = (const float*)d_in[2];
    const float* fcut        = (const float*)d_in[3];
    const float* rsh         = (const float*)d_in[4];
    const int*   eidx        = (const int*)d_in[5];
    const float* W1          = (const float*)d_in[6];
    const float* b1          = (const float*)d_in[7];
    const float* W2          = (const float*)d_in[8];
    const float* b2          = (const float*)d_in[9];
    const float* Wr          = (const float*)d_in[10];
    const float* br          = (const float*)d_in[11];

    float* out        = (float*)d_out;
    float* out_scalar = out;                                   // (N_NODES, 128)
    float* out_sph    = out + (size_t)N_NODES * NODE_DIM;      // (N_NODES, 480)

    // workspace layout
    unsigned short* so_bf   = (unsigned short*)d_ws;           // 10000*576 bf16
    int*   counts     = (int*)(so_bf + (size_t)N_NODES * HIDDEN);
    int*   offsets    = counts + N_NODES;                      // 10001
    int*   cursor     = offsets + N_NODES + 1;                 // 10000
    int*   edge_order = cursor + N_NODES;                      // 160000
    int*   edge_src   = edge_order + N_EDGES;                  // 160000
    unsigned short* bfrag = (unsigned short*)((((uintptr_t)(edge_src + N_EDGES)) + 15) & ~(uintptr_t)15);

    hipMemsetAsync(counts, 0, N_NODES * sizeof(int), stream);
    prep_mlp_kernel<<<PREP_BLOCKS + MLP_BLOCKS, 256, 0, stream>>>(
        x_scalar, x_spherical, out, eidx, counts, Wr, bfrag,
        W1, b1, W2, b2, so_bf);
    scan_kernel<<<1, 1024, 0, stream>>>(counts, offsets, cursor);
    scatter_kernel<<<(N_EDGES + 255) / 256, 256, 0, stream>>>(eidx, cursor, edge_order, edge_src);
    edge_mfma<<<N_EDGES / EB, 256, 0, stream>>>(x_spherical, rbf, fcut, rsh, eidx,
                                                bfrag, br, so_bf, edge_order, edge_src,
                                                out_scalar, out_sph);
}